// Round 5
// baseline (150.743 us; speedup 1.0000x reference)
//
#include <hip/hip_runtime.h>
#include <cstdint>
#include <cstddef>

#define BSZ 16
#define LQ  512
#define HIDDIM 768
#define NH  12
#define HD  64
#define R2V 16
#define NTOT 1536   // fused N: K cols [0,768) | V cols [768,1536)
#define MTOT 8192   // BSZ*LQ

typedef __bf16 bf16x8 __attribute__((ext_vector_type(8)));
typedef float  f32x4  __attribute__((ext_vector_type(4)));

__device__ inline unsigned short f2bf(float x) {
    union { float f; unsigned u; } c; c.f = x;
    unsigned r = c.u + 0x7fffu + ((c.u >> 16) & 1u);   // RNE (no NaN here)
    return (unsigned short)(r >> 16);
}
__device__ inline float bfl(unsigned u) { return __uint_as_float(u << 16); }
__device__ inline float bfh(unsigned u) { return __uint_as_float(u & 0xffff0000u); }

// ---------------------------------------------------------------------------
// Kernel 1 (FUSED cast+gemm): bf16 MFMA GEMM reading RAW fp32 inputs.
// 128x128 tile, BK=32, 256 thr = 4 waves, 16x16x32 MFMA, acc[4][4]/wave.
// Staging is reg-based (T14): load fp32 A/B panel chunk -> RNE-convert to
// bf16 in-register -> ds_write to the swizzled LDS layout.  Loads for tile
// t+2 are issued at iter t (one full iteration of flight ~= L2/HBM latency,
// hidden by MFMA + 3 blocks/CU TLP).  Raw s_barrier only — NO vmcnt(0)
// drain in the loop: the compiler emits counted vm-waits at the C-level
// register uses (CVT), so prefetch loads stay in flight across barriers.
// Write-before-read ordering inside each iter means the compiler's in-order
// lgkm wait before the MFMAs also drains this wave's ds_writes, so the raw
// barrier needs no extra lgkm drain.
// T2 involution swizzle on 16B units within each 64B row (verified R3/R4,
// conflicts=0): s(row)=(row>>1)&3; reg-staging writes DIRECTLY to the
// swizzled unit (u^s), fragment reads XOR the same term.
// T1 XCD remap (768 % 8 == 0, bijective, verified R4).
// Swapped-operand MFMA -> C^T; same k-order accumulation and RNE bf16
// inputs as the verified kernels -> bit-identical output.
// Bias is read directly from Kb/Vb in the epilogue (cast_pack eliminated).
// ---------------------------------------------------------------------------
#define TBM 128
#define TBN 128
#define TBK 32
#define KT  (HIDDIM / TBK)    // 24
#define ATILE (TBM * TBK)     // 4096 elements = 8 KB

#define CVT8(dstp, f0, f1) do {                                               \
        bf16x8 t_;                                                            \
        t_[0] = (__bf16)(f0).x; t_[1] = (__bf16)(f0).y;                       \
        t_[2] = (__bf16)(f0).z; t_[3] = (__bf16)(f0).w;                       \
        t_[4] = (__bf16)(f1).x; t_[5] = (__bf16)(f1).y;                       \
        t_[6] = (__bf16)(f1).z; t_[7] = (__bf16)(f1).w;                       \
        *reinterpret_cast<bf16x8*>(dstp) = t_;                                \
    } while (0)

__global__ __launch_bounds__(256, 3) void gemm_mfma(
    const float* __restrict__ hs,   // 8192 x 768 fp32
    const float* __restrict__ Kw,   // 768 x 768 fp32
    const float* __restrict__ Vw,   // 768 x 768 fp32
    const float* __restrict__ Kb, const float* __restrict__ Vb,
    unsigned short* __restrict__ K1b, unsigned short* __restrict__ V1b)
{
    __shared__ unsigned short As[2][ATILE];   // 16 KB
    __shared__ unsigned short Bs[2][ATILE];   // 16 KB

    // ---- T1: XCD-aware bijective remap (768 % 8 == 0) ----
    const int wg  = blockIdx.y * 12 + blockIdx.x;     // gridDim = (12, 64)
    const int nid = (wg & 7) * 96 + (wg >> 3);
    const int bx  = nid % 12;
    const int by  = nid / 12;
    const int n0  = bx * TBN;
    const int m0  = by * TBM;

    const bool isK = (n0 < HIDDIM);
    const float* __restrict__ Wsrc = isK ? Kw : Vw;
    const int nsub = isK ? 0 : HIDDIM;
    const int nb0  = n0 - nsub;

    const int tid  = threadIdx.x;
    const int wid  = tid >> 6;
    const int lane = tid & 63;
    const int wm   = (wid & 1) * 64;
    const int wn   = (wid >> 1) * 64;

    f32x4 acc[4][4] = {};   // lane holds m=lane&15, n-quad=(lane>>4)*4 (C^T)

    // ---- staging geometry: wave wid owns rows [wid*32, wid*32+32).
    // lane -> row rr = lane>>1 (0..31), half kh = lane&1 (16 fp32 each).
    // LDS row ra; swizzle s(ra) = (ra>>1)&3 over the four 8-elem units.
    const int rr = lane >> 1;
    const int kh = lane & 1;
    const int r0 = wid * 32;
    const int ra = r0 + rr;
    const int sw = (ra >> 1) & 3;
    const int u0 = ((2 * kh) ^ sw) * 8;       // element offset of unit 2kh
    const int u1 = ((2 * kh + 1) ^ sw) * 8;   // element offset of unit 2kh+1

    const float* Ag = hs   + (size_t)(m0  + ra) * HIDDIM + kh * 16;
    const float* Bg = Wsrc + (size_t)(nb0 + ra) * HIDDIM + kh * 16;

    // ---- fragment read geometry (swizzled; verified R3/R4) ----
    const int fm   = lane & 15;                         // M/N index in frag
    const int fj   = lane >> 4;                         // 0..3 : k-subgroup
    const int koff = ((fj ^ ((fm >> 1) & 3)) << 3);     // swizzled elem off

    float4 a0, a1, a2, a3, b0, b1, b2, b3;

#define LOADG(kt) do {                                                        \
        const float4* pa_ = (const float4*)(Ag + (kt) * TBK);                 \
        a0 = pa_[0]; a1 = pa_[1]; a2 = pa_[2]; a3 = pa_[3];                   \
        const float4* pb_ = (const float4*)(Bg + (kt) * TBK);                 \
        b0 = pb_[0]; b1 = pb_[1]; b2 = pb_[2]; b3 = pb_[3];                   \
    } while (0)

#define CVTWRITE(buf) do {                                                    \
        CVT8(&As[buf][ra * TBK + u0], a0, a1);                                \
        CVT8(&As[buf][ra * TBK + u1], a2, a3);                                \
        CVT8(&Bs[buf][ra * TBK + u0], b0, b1);                                \
        CVT8(&Bs[buf][ra * TBK + u1], b2, b3);                                \
    } while (0)

    // ---- prologue: tile 0 staged to buf 0; tile 1 loads in flight ----
    LOADG(0);
    CVTWRITE(0);
    LOADG(1);
    asm volatile("s_waitcnt lgkmcnt(0)" ::: "memory");
    __builtin_amdgcn_sched_barrier(0);

    for (int kt = 0; kt < KT; ++kt) {
        __builtin_amdgcn_s_barrier();        // raw: vm prefetch stays in flight
        __builtin_amdgcn_sched_barrier(0);
        const int cb = kt & 1;

        if (kt + 1 < KT) {
            CVTWRITE(cb ^ 1);                // tile kt+1 (regs from iter kt-1)
            if (kt + 2 < KT) LOADG(kt + 2);  // reuse regs; one iter of flight
        }

        bf16x8 af[4], bfr[4];
        #pragma unroll
        for (int mi = 0; mi < 4; ++mi)
            af[mi] = *reinterpret_cast<const bf16x8*>(
                &As[cb][(wm + mi * 16 + fm) * TBK + koff]);
        #pragma unroll
        for (int ni = 0; ni < 4; ++ni)
            bfr[ni] = *reinterpret_cast<const bf16x8*>(
                &Bs[cb][(wn + ni * 16 + fm) * TBK + koff]);
        __builtin_amdgcn_s_setprio(1);
        #pragma unroll
        for (int mi = 0; mi < 4; ++mi)
            #pragma unroll
            for (int ni = 0; ni < 4; ++ni)
                acc[mi][ni] = __builtin_amdgcn_mfma_f32_16x16x32_bf16(
                    bfr[ni], af[mi], acc[mi][ni], 0, 0, 0);   // swapped: C^T
        __builtin_amdgcn_s_setprio(0);
    }
#undef LOADG
#undef CVTWRITE

    // epilogue: lane holds m = fm, n = fj*4 + r (4 consecutive)
    unsigned short* __restrict__ dst = isK ? K1b : V1b;
    const float* __restrict__ bsrc   = isK ? Kb : Vb;
    const int nq = fj * 4;

    #pragma unroll
    for (int mi = 0; mi < 4; ++mi) {
        const int mg = m0 + wm + mi * 16 + fm;
        #pragma unroll
        for (int ni = 0; ni < 4; ++ni) {
            const int ng = n0 + wn + ni * 16 + nq;
            float4 bv = *(const float4*)(bsrc + (ng - nsub));
            f32x4 a = acc[mi][ni];
            ushort4 o;
            o.x = f2bf(fmaxf(a[0] + bv.x, 0.f));
            o.y = f2bf(fmaxf(a[1] + bv.y, 0.f));
            o.z = f2bf(fmaxf(a[2] + bv.z, 0.f));
            o.w = f2bf(fmaxf(a[3] + bv.w, 0.f));
            *(ushort4*)(dst + (size_t)mg * HIDDIM + (ng - nsub)) = o;
        }
    }
}

// ---------------------------------------------------------------------------
// Kernel 2: fused per (b,h): scores -> softmax(+exp(-m)) -> events -> scans
// -> idx (LDS) -> gather from V1b -> out.  512 threads = 8 waves.
// 4 blocks per (b,h): all run the cheap score/scan phases redundantly,
// each gathers 2 of 8 rounds (occupancy for the L2-latency-bound gather).
// ---------------------------------------------------------------------------
#define SINF (1 << 30)
#define IXP 17   // idxs row stride (pad 16->17)

__global__ __launch_bounds__(512) void scan_gather(
    const unsigned short* __restrict__ K1b,
    const unsigned short* __restrict__ V1b,
    const float* __restrict__ rh,
    const float* __restrict__ bw,
    float* __restrict__ out)
{
    const int bh   = blockIdx.x >> 2;  // 0..191
    const int part = blockIdx.x & 3;   // which pair of gather rounds
    const int b    = bh / NH;
    const int h    = bh % NH;
    const int l    = threadIdx.x;      // 0..511
    const int lane = l & 63;
    const int wid  = l >> 6;

    __shared__ float wredA[8];
    __shared__ float wredB[8];
    __shared__ int   wp0[8];
    __shared__ int   wp1[8];
    __shared__ int   wp2[8];
    __shared__ int   ev[LQ];
    __shared__ int   col0[LQ];
    __shared__ int   col1[LQ];
    __shared__ int   E[LQ];
    __shared__ int   idxs[LQ * IXP];   // ~34.8 KB
    __shared__ float wsm[R2V];

    if (l < R2V) wsm[l] = bw[h * R2V + l];

    // ---- 1. score: dot64(bf16 K1 row, fp32 reading_head) ----
    const unsigned short* krow = K1b + ((size_t)(b * LQ + l)) * HIDDIM + h * HD;
    const float* rrow = rh + h * HD;
    float s = 0.f;
    #pragma unroll
    for (int c8 = 0; c8 < 8; ++c8) {
        uint4 kv = *(const uint4*)(krow + c8 * 8);
        float4 ra = *(const float4*)(rrow + c8 * 8);
        float4 rb = *(const float4*)(rrow + c8 * 8 + 4);
        s += bfl(kv.x) * ra.x + bfh(kv.x) * ra.y
           + bfl(kv.y) * ra.z + bfh(kv.y) * ra.w
           + bfl(kv.z) * rb.x + bfh(kv.z) * rb.y
           + bfl(kv.w) * rb.z + bfh(kv.w) * rb.w;
    }

    // ---- 2. max reduce ----
    float mx = s;
    #pragma unroll
    for (int off = 32; off > 0; off >>= 1) mx = fmaxf(mx, __shfl_xor(mx, off));
    if (lane == 0) wredA[wid] = mx;
    __syncthreads();
    float m = wredA[0];
    #pragma unroll
    for (int i = 1; i < 8; ++i) m = fmaxf(m, wredA[i]);

    // ---- 3. sum reduce ----
    const float e = expf(s - m);
    float sm = e;
    #pragma unroll
    for (int off = 32; off > 0; off >>= 1) sm += __shfl_xor(sm, off);
    if (lane == 0) wredB[wid] = sm;
    __syncthreads();
    float ssum = 0.f;
    #pragma unroll
    for (int i = 0; i < 8; ++i) ssum += wredB[i];

    const float p = e / ssum + expf(-m);
    const int event = (p > (1.5f / 512.0f)) ? 1 : 0;
    ev[l] = event;

    // ---- 4. col0: inclusive max-scan of (event ? l : -1) ----
    int v = event ? l : -1;
    #pragma unroll
    for (int off = 1; off < 64; off <<= 1) {
        int u = __shfl_up(v, off);
        if (lane >= off) v = (u > v) ? u : v;
    }
    if (lane == 63) wp0[wid] = v;
    __syncthreads();                     // ev + wp0 visible
    int pfx = -1;
    for (int i = 0; i < wid; ++i) pfx = (wp0[i] > pfx) ? wp0[i] : pfx;
    v = (pfx > v) ? pfx : v;
    col0[l] = (v >= 0) ? v : l;

    // ---- 5. col1: suffix min-scan of (ev[(l+1)&511] ? l : INF) ----
    int v1 = ev[(l + 1) & (LQ - 1)] ? l : SINF;
    #pragma unroll
    for (int off = 1; off < 64; off <<= 1) {
        int u = __shfl_down(v1, off);
        if (lane < 64 - off) v1 = (u < v1) ? u : v1;
    }
    if (lane == 0) wp1[wid] = v1;
    __syncthreads();
    int sfx = SINF;
    for (int i = wid + 1; i < 8; ++i) sfx = (wp1[i] < sfx) ? wp1[i] : sfx;
    v1 = (sfx < v1) ? sfx : v1;
    col1[l] = (l == 0) ? 0 : (((v1 < SINF) ? v1 : l) + 1);

    // ---- 6. prefix count of events over steps 1..l ----
    int c = (l >= 1) ? event : 0;
    #pragma unroll
    for (int off = 1; off < 64; off <<= 1) {
        int u = __shfl_up(c, off);
        if (lane >= off) c += u;
    }
    if (lane == 63) wp2[wid] = c;
    __syncthreads();
    for (int i = 0; i < wid; ++i) c += wp2[i];

    // ---- 7. event-time list ----
    if (l >= 1 && event) E[c - 1] = l;
    __syncthreads();                     // E, col0, col1 ready

    // ---- 8. idx registers -> LDS ----
    int* op = &idxs[l * IXP];
    #pragma unroll
    for (int j = 0; j < 8; ++j) {
        const int k = c - 1 - j;
        int f = 0, bb = 0;
        if (k >= 0) {
            const int t = E[k];          // t >= 1
            f  = col0[t - 1];
            bb = col1[t - 1];
        }
        op[2 * j]     = min(max(f, 0), LQ - 1);
        op[2 * j + 1] = min(max(bb, 0), LQ - 1);
    }
    __syncthreads();                     // idxs + wsm ready

    // ---- 9. gather: 8 lanes per l (dsl covers 8 d's), this block's 2 of 8
    //         rounds, 4-chunked ----
    const int dsl = lane & 7;
    const size_t vbase = (size_t)b * LQ * HIDDIM + h * HD + dsl * 8;

    for (int rr = 0; rr < 2; ++rr) {
        const int round = part * 2 + rr;
        const int lg = round * 64 + wid * 8 + (lane >> 3);
        const int* ip = &idxs[lg * IXP];
        float a0 = 0.f, a1 = 0.f, a2 = 0.f, a3 = 0.f;
        float a4 = 0.f, a5 = 0.f, a6 = 0.f, a7 = 0.f;
        #pragma unroll 1
        for (int rc = 0; rc < R2V; rc += 4) {
            const int i0 = ip[rc], i1 = ip[rc + 1], i2 = ip[rc + 2], i3 = ip[rc + 3];
            uint4 v0 = *(const uint4*)(V1b + vbase + (size_t)i0 * HIDDIM);
            uint4 vA = *(const uint4*)(V1b + vbase + (size_t)i1 * HIDDIM);
            uint4 vB = *(const uint4*)(V1b + vbase + (size_t)i2 * HIDDIM);
            uint4 vC = *(const uint4*)(V1b + vbase + (size_t)i3 * HIDDIM);
            const float w0 = wsm[rc], w1 = wsm[rc + 1], w2 = wsm[rc + 2], w3 = wsm[rc + 3];
            a0 += w0 * bfl(v0.x); a1 += w0 * bfh(v0.x);
            a2 += w0 * bfl(v0.y); a3 += w0 * bfh(v0.y);
            a4 += w0 * bfl(v0.z); a5 += w0 * bfh(v0.z);
            a6 += w0 * bfl(v0.w); a7 += w0 * bfh(v0.w);
            a0 += w1 * bfl(vA.x); a1 += w1 * bfh(vA.x);
            a2 += w1 * bfl(vA.y); a3 += w1 * bfh(vA.y);
            a4 += w1 * bfl(vA.z); a5 += w1 * bfh(vA.z);
            a6 += w1 * bfl(vA.w); a7 += w1 * bfh(vA.w);
            a0 += w2 * bfl(vB.x); a1 += w2 * bfh(vB.x);
            a2 += w2 * bfl(vB.y); a3 += w2 * bfh(vB.y);
            a4 += w2 * bfl(vB.z); a5 += w2 * bfh(vB.z);
            a6 += w2 * bfl(vB.w); a7 += w2 * bfh(vB.w);
            a0 += w3 * bfl(vC.x); a1 += w3 * bfh(vC.x);
            a2 += w3 * bfl(vC.y); a3 += w3 * bfh(vC.y);
            a4 += w3 * bfl(vC.z); a5 += w3 * bfh(vC.z);
            a6 += w3 * bfl(vC.w); a7 += w3 * bfh(vC.w);
        }
        float* po = out + ((size_t)(b * LQ + lg) * NH + h) * HD + dsl * 8;
        *(float4*)po       = make_float4(a0, a1, a2, a3);
        *((float4*)po + 1) = make_float4(a4, a5, a6, a7);
    }
}

// ---------------------------------------------------------------------------
extern "C" void kernel_launch(void* const* d_in, const int* in_sizes, int n_in,
                              void* d_out, int out_size, void* d_ws, size_t ws_size,
                              hipStream_t stream)
{
    (void)in_sizes; (void)n_in; (void)out_size; (void)ws_size;

    const float* hs = (const float*)d_in[0];
    const float* Kw = (const float*)d_in[1];
    const float* Kb = (const float*)d_in[2];
    const float* Vw = (const float*)d_in[3];
    const float* Vb = (const float*)d_in[4];
    const float* rh = (const float*)d_in[5];
    const float* bw = (const float*)d_in[6];
    float* out = (float*)d_out;

    // ws layout (bytes):
    //   K1b  bf16 8192*768  @ 0         (12.58 MB)
    //   V1b  bf16 8192*768  @ 12582912  (12.58 MB)
    char* ws = (char*)d_ws;
    unsigned short* K1b = (unsigned short*)(ws);
    unsigned short* V1b = (unsigned short*)(ws + 12582912);

    dim3 g1(NTOT / TBN, MTOT / TBM);   // 12 x 64 = 768 blocks, 3 blocks/CU
    gemm_mfma<<<g1, 256, 0, stream>>>(hs, Kw, Vw, Kb, Vb, K1b, V1b);

    scan_gather<<<BSZ * NH * 4, LQ, 0, stream>>>(K1b, V1b, rh, bw, out);
}